// Round 2
// baseline (569.657 us; speedup 1.0000x reference)
//
#include <hip/hip_runtime.h>
#include <hip/hip_bf16.h>
#include <math.h>

#define NBAND 8
#define K1_THREADS 1024
#define CHUNK 128
#define HALO  192
#define TILE  16

struct Params {
  float lags[NBAND];
  float amps[NBAND];
  float a, c, kphi1, kphi2;
  int bandstart[NBAND];
  int nb[NBAND];
  int blkbase[NBAND + 1];
};

// ---------------- K1: per-block band histogram (ballot, no atomics) ----------------
__global__ void k1_hist(const int* __restrict__ band, int* __restrict__ cnt) {
  __shared__ int wc[16][NBAND];
  int tid = threadIdx.x;
  int i = blockIdx.x * K1_THREADS + tid;
  int b = band[i];
  int lane = tid & 63, w = tid >> 6;
#pragma unroll
  for (int bb = 0; bb < NBAND; ++bb) {
    unsigned long long m = __ballot(b == bb);
    if (lane == bb) wc[w][bb] = __popcll(m);
  }
  __syncthreads();
  if (tid < NBAND) {
    int s = 0;
#pragma unroll
    for (int w2 = 0; w2 < 16; ++w2) s += wc[w2][tid];
    cnt[blockIdx.x * NBAND + tid] = s;
  }
}

// ---------------- K2: scan block counts -> offsets; also init params + acc ----------------
// 1 block, 1024 threads. band b = tid>>7, segment seg = tid&127, nblk/128 blocks per thread.
__global__ void k2_scan(const int* __restrict__ cnt, int* __restrict__ boff,
                        Params* __restrict__ P, int nblk,
                        const float* __restrict__ lad, const float* __restrict__ lag,
                        const float* __restrict__ lkp, double* __restrict__ acc) {
  __shared__ int sd[1024];
  __shared__ int tot[NBAND], bstart[NBAND];
  int tid = threadIdx.x;
  if (tid == 0) {
    P->lags[0] = 0.f;
    P->amps[0] = 1.f;
    for (int j = 0; j < NBAND - 1; ++j) {
      P->lags[j + 1] = lag[j];
      P->amps[j + 1] = expf(lad[j]);
    }
    float a = expf(lkp[0]);
    float c = expf(lkp[1]);
    P->a = a;
    P->c = c;
    P->kphi1 = -c * 1.4426950408889634f;
    P->kphi2 = -2.f * c * 1.4426950408889634f;
    acc[0] = 0.0;
    acc[1] = 0.0;
  }
  int b = tid >> 7, seg = tid & 127;
  int per = nblk / 128;
  int blk0 = seg * per;
  int sum = 0;
  for (int u = 0; u < per; ++u) sum += cnt[(blk0 + u) * NBAND + b];
  int val = sum;
  sd[tid] = val;
  __syncthreads();
  for (int off = 1; off < 128; off <<= 1) {
    int yv = (seg >= off) ? sd[tid - off] : 0;
    __syncthreads();
    val += yv;
    sd[tid] = val;
    __syncthreads();
  }
  if (seg == 127) tot[b] = val;
  __syncthreads();
  if (tid == 0) {
    int g = 0;
    for (int bb = 0; bb < NBAND; ++bb) {
      bstart[bb] = g;
      P->bandstart[bb] = g;
      P->nb[bb] = tot[bb];
      g += tot[bb];
    }
    int s = 0;
    for (int bb = 0; bb < NBAND; ++bb) {
      P->blkbase[bb] = s;
      s += (tot[bb] + 255) / 256;
    }
    P->blkbase[NBAND] = s;
  }
  __syncthreads();
  int run = bstart[b] + (val - sum);
  for (int u = 0; u < per; ++u) {
    int idx = (blk0 + u) * NBAND + b;
    int x = cnt[idx];
    boff[idx] = run;
    run += x;
  }
}

// ---------------- K3: stable scatter of full payload (t,y,diag,amp) into band partition ----
__global__ void k3_scatter(const float* __restrict__ t, const int* __restrict__ band,
                           const float* __restrict__ y, const float* __restrict__ dg,
                           const int* __restrict__ boff, const Params* __restrict__ P,
                           float4* __restrict__ payload) {
  __shared__ int wc[16][NBAND];
  int tid = threadIdx.x;
  int i = blockIdx.x * K1_THREADS + tid;
  int b = band[i];
  float v = t[i] - P->lags[b];
  int lane = tid & 63, w = tid >> 6;
  int lower = 0;
#pragma unroll
  for (int bb = 0; bb < NBAND; ++bb) {
    unsigned long long m = __ballot(b == bb);
    if (lane == bb) wc[w][bb] = __popcll(m);
    if (b == bb) lower = __popcll(m & ((1ull << lane) - 1ull));
  }
  __syncthreads();
  int base = 0;
  for (int w2 = 0; w2 < w; ++w2) base += wc[w2][b];
  int pos = boff[blockIdx.x * NBAND + b] + base + lower;
  payload[pos] = make_float4(v, y[i], dg[i], P->amps[b]);
}

// ---------------- K4: 8-way-merge rank + scatter payload to sorted order ----------------
__global__ void k4_rank(const float4* __restrict__ payload, const Params* __restrict__ P,
                        float4* __restrict__ out4) {
  __shared__ int bnd[7][2];
  __shared__ int sbs[NBAND], snb[NBAND];
  int tid = threadIdx.x;
  int bid = blockIdx.x;
  int total = P->blkbase[NBAND];
  if (bid >= total) return;
  if (tid < NBAND) {
    sbs[tid] = P->bandstart[tid];
    snb[tid] = P->nb[tid];
  }
  int b0 = 0;
  for (int b = 1; b < NBAND; ++b)
    if (bid >= P->blkbase[b]) b0 = b;
  int chunk = bid - P->blkbase[b0];
  __syncthreads();
  int q0 = chunk * 256;
  int bs0 = sbs[b0];
  int m = min(256, snb[b0] - q0);
  // bracket: threads 0..13 do the 7x2 global binary searches
  if (tid < 14) {
    int j = tid >> 1, which = tid & 1;
    int bo = j + (j >= b0);
    float v = payload[bs0 + q0 + (which ? (m - 1) : 0)].x;
    bool le = (bo < b0);  // key order (value, band)
    const float4* p = payload + sbs[bo];
    int lo = 0, hi = snb[bo];
    while (lo < hi) {
      int mid = (lo + hi) >> 1;
      float w = p[mid].x;
      bool pr = le ? (w <= v) : (w < v);
      if (pr) lo = mid + 1; else hi = mid;
    }
    bnd[j][which] = lo;
  }
  __syncthreads();
  if (tid < m) {
    float4 pl = payload[bs0 + q0 + tid];
    float v = pl.x;
    int rank = q0 + tid;
    int lo[7], hi[7], bs[7];
    bool le[7];
#pragma unroll
    for (int j = 0; j < 7; ++j) {
      int bo = j + (j >= b0);
      lo[j] = bnd[j][0];
      hi[j] = bnd[j][1];
      bs[j] = sbs[bo];
      le[j] = (bo < b0);
    }
    bool any = true;
    while (any) {
      any = false;
#pragma unroll
      for (int j = 0; j < 7; ++j) {
        if (lo[j] < hi[j]) {
          int mid = (lo[j] + hi[j]) >> 1;
          float w = payload[bs[j] + mid].x;
          bool pr = le[j] ? (w <= v) : (w < v);
          if (pr) lo[j] = mid + 1; else hi[j] = mid;
          if (lo[j] < hi[j]) any = true;
        }
      }
    }
#pragma unroll
    for (int j = 0; j < 7; ++j) rank += lo[j];
    out4[rank] = pl;
  }
}

// ---------------- K5: chunked celerite scan with halo warm-up ----------------
struct ScanState {
  float Sp, fp, tprev, s1, s2;
};

template <bool ACCUM>
__device__ __forceinline__ void step_one(float4 v, ScanState& st, float a, float k1c,
                                         float k2c) {
  float t = v.x, yv = v.y, d = v.z, amp = v.w;
  float dt = t - st.tprev;
  st.tprev = t;
  float e2 = __builtin_amdgcn_exp2f(k2c * dt);  // phi^2
  float e1 = __builtin_amdgcn_exp2f(k1c * dt);  // phi
  float U = a * amp;
  float aa2 = U * amp;        // a*amp^2 = U*V
  float Aa = d + aa2;         // diagonal A
  float c1 = d - aa2;         // A - 2UV
  float V2 = amp * amp;
  float x = e2 * st.Sp;       // S_n
  float D = fmaf(-(U * U), x, Aa);
  float r = __builtin_amdgcn_rcpf(D);
  float num = fmaf(c1, x, V2);
  st.Sp = num * r;            // Moebius form of S + D*W^2
  float f = e1 * st.fp;
  float z = fmaf(-U, f, yv);
  float Wn = fmaf(-U, x, amp);  // V - U*S
  float W = Wn * r;
  st.fp = fmaf(W, z, f);
  if (ACCUM) {
    st.s1 = fmaf(z * z, r, st.s1);
    st.s2 += __builtin_amdgcn_logf(D);  // log2(D)
  }
}

template <bool ACCUM>
__device__ __forceinline__ void run_range(const float4* __restrict__ q, long s, long e,
                                          ScanState& st, float a, float k1c, float k2c) {
  float4 A[TILE], B[TILE];
#pragma unroll
  for (int u = 0; u < TILE; ++u) A[u] = q[s + u];
  for (long tb = s; tb < e; tb += 2 * TILE) {
#pragma unroll
    for (int u = 0; u < TILE; ++u) B[u] = q[tb + TILE + u];
#pragma unroll
    for (int u = 0; u < TILE; ++u) step_one<ACCUM>(A[u], st, a, k1c, k2c);
#pragma unroll
    for (int u = 0; u < TILE; ++u) A[u] = q[tb + 2 * TILE + u];  // prefetch next
#pragma unroll
    for (int u = 0; u < TILE; ++u) step_one<ACCUM>(B[u], st, a, k1c, k2c);
  }
}

__global__ __launch_bounds__(64, 1) void k5_scan(const float4* __restrict__ q,
                                                 const Params* __restrict__ P,
                                                 double* __restrict__ acc) {
  int k = blockIdx.x * 64 + threadIdx.x;
  long base = (long)k * CHUNK;
  float a = P->a, k1c = P->kphi1, k2c = P->kphi2;
  ScanState st;
  st.Sp = 0.f;
  st.fp = 0.f;
  st.s1 = 0.f;
  st.s2 = 0.f;
  long s0 = (k == 0) ? base : (base - HALO);
  st.tprev = q[s0].x;  // first dt = 0 (matches reference prepend for k==0)
  if (k > 0) run_range<false>(q, base - HALO, base, st, a, k1c, k2c);
  run_range<true>(q, base, base + CHUNK, st, a, k1c, k2c);
  float s1 = st.s1, s2 = st.s2;
#pragma unroll
  for (int off = 32; off > 0; off >>= 1) {
    s1 += __shfl_down(s1, off);
    s2 += __shfl_down(s2, off);
  }
  if (threadIdx.x == 0) {
    atomicAdd(&acc[0], (double)s1);
    atomicAdd(&acc[1], (double)s2);
  }
}

// ---------------- K6: finalize ----------------
__global__ void k6_final(const double* __restrict__ acc, float* __restrict__ out, long n) {
  double r = 0.5 * (acc[0] + acc[1] * 0.6931471805599453 +
                    (double)n * 1.8378770664093453);
  out[0] = (float)r;
}

extern "C" void kernel_launch(void* const* d_in, const int* in_sizes, int n_in,
                              void* d_out, int out_size, void* d_ws, size_t ws_size,
                              hipStream_t stream) {
  const float* t = (const float*)d_in[0];
  const int* band = (const int*)d_in[1];
  const float* y = (const float*)d_in[2];
  const float* dg = (const float*)d_in[3];
  const float* lad = (const float*)d_in[4];
  const float* lag = (const float*)d_in[5];
  const float* lkp = (const float*)d_in[6];
  float* out = (float*)d_out;
  long N = in_sizes[0];

  char* ws = (char*)d_ws;
  Params* P = (Params*)(ws + 0);
  double* acc = (double*)(ws + 1024);
  int* cnt = (int*)(ws + 8192);
  long nblk = N / K1_THREADS;  // 4096
  int* boff = (int*)(ws + 8192 + nblk * NBAND * 4);
  // out4 FIRST so k5's tail prefetch over-read lands inside payload (safe),
  // not past the end of ws.
  float4* out4 = (float4*)(ws + 524288);
  float4* payload = (float4*)(ws + 524288 + (size_t)N * 16);
  // total ws need: 524288 + N*16 + N*16  (~128.5 MB for N=4.19M)

  k1_hist<<<(int)nblk, K1_THREADS, 0, stream>>>(band, cnt);
  k2_scan<<<1, 1024, 0, stream>>>(cnt, boff, P, (int)nblk, lad, lag, lkp, acc);
  k3_scatter<<<(int)nblk, K1_THREADS, 0, stream>>>(t, band, y, dg, boff, P, payload);
  long nb4 = N / 256 + NBAND;  // a few blocks idle-exit
  k4_rank<<<(int)nb4, 256, 0, stream>>>(payload, P, out4);
  long T = N / CHUNK;  // 32768 scan threads
  k5_scan<<<(int)(T / 64), 64, 0, stream>>>(out4, P, acc);
  k6_final<<<1, 1, 0, stream>>>(acc, out, N);
}

// Round 3
// 408.783 us; speedup vs baseline: 1.3935x; 1.3935x over previous
//
#include <hip/hip_runtime.h>
#include <hip/hip_bf16.h>
#include <math.h>

#define NBAND 8
#define K1_THREADS 1024
#define CHUNK 128
#define HALO  192
#define TILE  16
#define WCAP  640   // per-band LDS probe-window cap (mean ~256, sd ~20)

struct Params {
  float lags[NBAND];
  float amps[NBAND];
  float a, c, kphi1, kphi2;
  int bandstart[NBAND];
  int nb[NBAND];
  int blkbase[NBAND + 1];
};

// ---------------- K1: per-block band histogram (ballot, no atomics) ----------------
__global__ void k1_hist(const int* __restrict__ band, int* __restrict__ cnt) {
  __shared__ int wc[16][NBAND];
  int tid = threadIdx.x;
  int i = blockIdx.x * K1_THREADS + tid;
  int b = band[i];
  int lane = tid & 63, w = tid >> 6;
#pragma unroll
  for (int bb = 0; bb < NBAND; ++bb) {
    unsigned long long m = __ballot(b == bb);
    if (lane == bb) wc[w][bb] = __popcll(m);
  }
  __syncthreads();
  if (tid < NBAND) {
    int s = 0;
#pragma unroll
    for (int w2 = 0; w2 < 16; ++w2) s += wc[w2][tid];
    cnt[blockIdx.x * NBAND + tid] = s;
  }
}

// ---------------- K2: scan block counts -> offsets; also init params + acc ----------------
__global__ void k2_scan(const int* __restrict__ cnt, int* __restrict__ boff,
                        Params* __restrict__ P, int nblk,
                        const float* __restrict__ lad, const float* __restrict__ lag,
                        const float* __restrict__ lkp, double* __restrict__ acc) {
  __shared__ int sd[1024];
  __shared__ int tot[NBAND], bstart[NBAND];
  int tid = threadIdx.x;
  if (tid == 0) {
    P->lags[0] = 0.f;
    P->amps[0] = 1.f;
    for (int j = 0; j < NBAND - 1; ++j) {
      P->lags[j + 1] = lag[j];
      P->amps[j + 1] = expf(lad[j]);
    }
    float a = expf(lkp[0]);
    float c = expf(lkp[1]);
    P->a = a;
    P->c = c;
    P->kphi1 = -c * 1.4426950408889634f;
    P->kphi2 = -2.f * c * 1.4426950408889634f;
    acc[0] = 0.0;
    acc[1] = 0.0;
  }
  int b = tid >> 7, seg = tid & 127;
  int per = nblk / 128;
  int blk0 = seg * per;
  int sum = 0;
  for (int u = 0; u < per; ++u) sum += cnt[(blk0 + u) * NBAND + b];
  int val = sum;
  sd[tid] = val;
  __syncthreads();
  for (int off = 1; off < 128; off <<= 1) {
    int yv = (seg >= off) ? sd[tid - off] : 0;
    __syncthreads();
    val += yv;
    sd[tid] = val;
    __syncthreads();
  }
  if (seg == 127) tot[b] = val;
  __syncthreads();
  if (tid == 0) {
    int g = 0;
    for (int bb = 0; bb < NBAND; ++bb) {
      bstart[bb] = g;
      P->bandstart[bb] = g;
      P->nb[bb] = tot[bb];
      g += tot[bb];
    }
    int s = 0;
    for (int bb = 0; bb < NBAND; ++bb) {
      P->blkbase[bb] = s;
      s += (tot[bb] + 255) / 256;
    }
    P->blkbase[NBAND] = s;
  }
  __syncthreads();
  int run = bstart[b] + (val - sum);
  for (int u = 0; u < per; ++u) {
    int idx = (blk0 + u) * NBAND + b;
    int x = cnt[idx];
    boff[idx] = run;
    run += x;
  }
}

// ---------------- K3: stable scatter of payload + packed keys into band partition ------
__global__ void k3_scatter(const float* __restrict__ t, const int* __restrict__ band,
                           const float* __restrict__ y, const float* __restrict__ dg,
                           const int* __restrict__ boff, const Params* __restrict__ P,
                           float4* __restrict__ payload, float* __restrict__ bt) {
  __shared__ int wc[16][NBAND];
  int tid = threadIdx.x;
  int i = blockIdx.x * K1_THREADS + tid;
  int b = band[i];
  float v = t[i] - P->lags[b];
  int lane = tid & 63, w = tid >> 6;
  int lower = 0;
#pragma unroll
  for (int bb = 0; bb < NBAND; ++bb) {
    unsigned long long m = __ballot(b == bb);
    if (lane == bb) wc[w][bb] = __popcll(m);
    if (b == bb) lower = __popcll(m & ((1ull << lane) - 1ull));
  }
  __syncthreads();
  int base = 0;
  for (int w2 = 0; w2 < w; ++w2) base += wc[w2][b];
  int pos = boff[blockIdx.x * NBAND + b] + base + lower;
  payload[pos] = make_float4(v, y[i], dg[i], P->amps[b]);
  bt[pos] = v;
}

// ---------------- K4: 8-way-merge rank via LDS-staged windows + scatter ----------------
__global__ void k4_rank(const float* __restrict__ bt, const float4* __restrict__ payload,
                        const Params* __restrict__ P, float4* __restrict__ out4) {
  __shared__ int bnd[7][2];
  __shared__ int sbs[NBAND], snb[NBAND], sblk[NBAND + 1];
  __shared__ float win[7][WCAP];
  int tid = threadIdx.x;
  int bid = blockIdx.x;
  if (tid < NBAND) {
    sbs[tid] = P->bandstart[tid];
    snb[tid] = P->nb[tid];
  }
  if (tid <= NBAND) sblk[tid] = P->blkbase[tid];
  __syncthreads();
  if (bid >= sblk[NBAND]) return;
  int b0 = 0;
#pragma unroll
  for (int b = 1; b < NBAND; ++b)
    if (bid >= sblk[b]) b0 = b;
  int chunk = bid - sblk[b0];
  int q0 = chunk * 256;
  int bs0 = sbs[b0];
  int m = min(256, snb[b0] - q0);
  // bracket: threads 0..13 do the 7x2 global binary searches on packed keys
  if (tid < 14) {
    int j = tid >> 1, which = tid & 1;
    int bo = j + (j >= b0);
    float v = bt[bs0 + q0 + (which ? (m - 1) : 0)];
    bool le = (bo < b0);  // key order (value, band)
    const float* p = bt + sbs[bo];
    int lo = 0, hi = snb[bo];
    while (lo < hi) {
      int mid = (lo + hi) >> 1;
      float w = p[mid];
      bool pr = le ? (w <= v) : (w < v);
      if (pr) lo = mid + 1; else hi = mid;
    }
    bnd[j][which] = lo;
  }
  __syncthreads();
  // stage the 7 probe windows into LDS (coalesced)
  bool fits = true;
#pragma unroll
  for (int j = 0; j < 7; ++j) {
    int bo = j + (j >= b0);
    int lo = bnd[j][0];
    int len = bnd[j][1] - lo;
    fits = fits && (len <= WCAP);
    int w = min(len, WCAP);
    const float* src = bt + sbs[bo] + lo;
    for (int u = tid; u < w; u += 256) win[j][u] = src[u];
  }
  __syncthreads();
  if (tid < m) {
    float4 pl = payload[bs0 + q0 + tid];
    float v = pl.x;
    int rank = q0 + tid;
    int lo[7], hi[7];
    bool le[7];
#pragma unroll
    for (int j = 0; j < 7; ++j) {
      lo[j] = 0;
      hi[j] = bnd[j][1] - bnd[j][0];
      int bo = j + (j >= b0);
      le[j] = (bo < b0);
    }
    if (fits) {
      // hot path: all probes in LDS, 7 searches advanced in lockstep
      bool any = true;
      while (any) {
        any = false;
#pragma unroll
        for (int j = 0; j < 7; ++j) {
          if (lo[j] < hi[j]) {
            int mid = (lo[j] + hi[j]) >> 1;
            float w = win[j][mid];
            bool pr = le[j] ? (w <= v) : (w < v);
            if (pr) lo[j] = mid + 1; else hi[j] = mid;
            if (lo[j] < hi[j]) any = true;
          }
        }
      }
    } else {
      // cold fallback (window overflow — p ~ 0): global probes
      int gb[7];
#pragma unroll
      for (int j = 0; j < 7; ++j) {
        int bo = j + (j >= b0);
        gb[j] = sbs[bo] + bnd[j][0];
      }
      bool any = true;
      while (any) {
        any = false;
#pragma unroll
        for (int j = 0; j < 7; ++j) {
          if (lo[j] < hi[j]) {
            int mid = (lo[j] + hi[j]) >> 1;
            float w = bt[gb[j] + mid];
            bool pr = le[j] ? (w <= v) : (w < v);
            if (pr) lo[j] = mid + 1; else hi[j] = mid;
            if (lo[j] < hi[j]) any = true;
          }
        }
      }
    }
#pragma unroll
    for (int j = 0; j < 7; ++j) rank += lo[j] + bnd[j][0];
    out4[rank] = pl;
  }
}

// ---------------- K5: chunked celerite scan with halo warm-up ----------------
struct ScanState {
  float Sp, fp, tprev, s1, s2;
};

template <bool ACCUM>
__device__ __forceinline__ void step_one(float4 v, ScanState& st, float a, float k1c,
                                         float k2c) {
  float t = v.x, yv = v.y, d = v.z, amp = v.w;
  float dt = t - st.tprev;
  st.tprev = t;
  float e2 = __builtin_amdgcn_exp2f(k2c * dt);  // phi^2
  float e1 = __builtin_amdgcn_exp2f(k1c * dt);  // phi
  float U = a * amp;
  float aa2 = U * amp;        // a*amp^2 = U*V
  float Aa = d + aa2;         // diagonal A
  float c1 = d - aa2;         // A - 2UV
  float V2 = amp * amp;
  float x = e2 * st.Sp;       // S_n
  float D = fmaf(-(U * U), x, Aa);
  float r = __builtin_amdgcn_rcpf(D);
  float num = fmaf(c1, x, V2);
  st.Sp = num * r;            // Moebius form of S + D*W^2
  float f = e1 * st.fp;
  float z = fmaf(-U, f, yv);
  float Wn = fmaf(-U, x, amp);  // V - U*S
  float W = Wn * r;
  st.fp = fmaf(W, z, f);
  if (ACCUM) {
    st.s1 = fmaf(z * z, r, st.s1);
    st.s2 += __builtin_amdgcn_logf(D);  // log2(D)
  }
}

template <bool ACCUM>
__device__ __forceinline__ void run_range(const float4* __restrict__ q, long s, long e,
                                          ScanState& st, float a, float k1c, float k2c) {
  float4 A[TILE], B[TILE];
#pragma unroll
  for (int u = 0; u < TILE; ++u) A[u] = q[s + u];
  for (long tb = s; tb < e; tb += 2 * TILE) {
#pragma unroll
    for (int u = 0; u < TILE; ++u) B[u] = q[tb + TILE + u];
#pragma unroll
    for (int u = 0; u < TILE; ++u) step_one<ACCUM>(A[u], st, a, k1c, k2c);
#pragma unroll
    for (int u = 0; u < TILE; ++u) A[u] = q[tb + 2 * TILE + u];  // prefetch next
#pragma unroll
    for (int u = 0; u < TILE; ++u) step_one<ACCUM>(B[u], st, a, k1c, k2c);
  }
}

__global__ __launch_bounds__(64, 1) void k5_scan(const float4* __restrict__ q,
                                                 const Params* __restrict__ P,
                                                 double* __restrict__ acc) {
  int k = blockIdx.x * 64 + threadIdx.x;
  long base = (long)k * CHUNK;
  float a = P->a, k1c = P->kphi1, k2c = P->kphi2;
  ScanState st;
  st.Sp = 0.f;
  st.fp = 0.f;
  st.s1 = 0.f;
  st.s2 = 0.f;
  long s0 = (k == 0) ? base : (base - HALO);
  st.tprev = q[s0].x;  // first dt = 0 (matches reference prepend for k==0)
  if (k > 0) run_range<false>(q, base - HALO, base, st, a, k1c, k2c);
  run_range<true>(q, base, base + CHUNK, st, a, k1c, k2c);
  float s1 = st.s1, s2 = st.s2;
#pragma unroll
  for (int off = 32; off > 0; off >>= 1) {
    s1 += __shfl_down(s1, off);
    s2 += __shfl_down(s2, off);
  }
  if (threadIdx.x == 0) {
    atomicAdd(&acc[0], (double)s1);
    atomicAdd(&acc[1], (double)s2);
  }
}

// ---------------- K6: finalize ----------------
__global__ void k6_final(const double* __restrict__ acc, float* __restrict__ out, long n) {
  double r = 0.5 * (acc[0] + acc[1] * 0.6931471805599453 +
                    (double)n * 1.8378770664093453);
  out[0] = (float)r;
}

extern "C" void kernel_launch(void* const* d_in, const int* in_sizes, int n_in,
                              void* d_out, int out_size, void* d_ws, size_t ws_size,
                              hipStream_t stream) {
  const float* t = (const float*)d_in[0];
  const int* band = (const int*)d_in[1];
  const float* y = (const float*)d_in[2];
  const float* dg = (const float*)d_in[3];
  const float* lad = (const float*)d_in[4];
  const float* lag = (const float*)d_in[5];
  const float* lkp = (const float*)d_in[6];
  float* out = (float*)d_out;
  long N = in_sizes[0];

  char* ws = (char*)d_ws;
  Params* P = (Params*)(ws + 0);
  double* acc = (double*)(ws + 1024);
  int* cnt = (int*)(ws + 8192);
  long nblk = N / K1_THREADS;  // 4096
  int* boff = (int*)(ws + 8192 + nblk * NBAND * 4);
  // layout: out4 first so k5's tail prefetch over-read lands inside payload (safe)
  float4* out4 = (float4*)(ws + 524288);
  float4* payload = (float4*)(ws + 524288 + (size_t)N * 16);
  float* bt = (float*)(ws + 524288 + (size_t)N * 32);
  // total ws need: 524288 + N*16 + N*16 + N*4  (~144.5 MB for N=4.19M)

  k1_hist<<<(int)nblk, K1_THREADS, 0, stream>>>(band, cnt);
  k2_scan<<<1, 1024, 0, stream>>>(cnt, boff, P, (int)nblk, lad, lag, lkp, acc);
  k3_scatter<<<(int)nblk, K1_THREADS, 0, stream>>>(t, band, y, dg, boff, P, payload, bt);
  long nb4 = N / 256 + NBAND;  // a few blocks idle-exit
  k4_rank<<<(int)nb4, 256, 0, stream>>>(bt, payload, P, out4);
  long T = N / CHUNK;  // 32768 scan threads
  k5_scan<<<(int)(T / 64), 64, 0, stream>>>(out4, P, acc);
  k6_final<<<1, 1, 0, stream>>>(acc, out, N);
}

// Round 5
// 299.126 us; speedup vs baseline: 1.9044x; 1.3666x over previous
//
#include <hip/hip_runtime.h>
#include <hip/hip_bf16.h>
#include <math.h>

#define NBAND 8
#define K1_THREADS 1024
#define CHUNK 128
#define HALO  192
#define TILE  16
#define OUTBLK 2048          // merged outputs per k4 block (mean)
#define MCAP   3072          // LDS record capacity (mean 2048, sd ~45 with value splitters)

struct Params {
  float lags[NBAND];
  float amps[NBAND];
  float a, c, kphi1, kphi2;
  int bandstart[NBAND];
  int nb[NBAND];
  int blkbase[NBAND + 1];
};

__device__ __forceinline__ unsigned f2u(float f) {
  unsigned b = __float_as_uint(f);
  return b ^ ((b >> 31) ? 0xFFFFFFFFu : 0x80000000u);
}

// ---------------- K1: per-block band histogram (ballot, no atomics) ----------------
__global__ void k1_hist(const int* __restrict__ band, int* __restrict__ cnt) {
  __shared__ int wc[16][NBAND];
  int tid = threadIdx.x;
  int i = blockIdx.x * K1_THREADS + tid;
  int b = band[i];
  int lane = tid & 63, w = tid >> 6;
#pragma unroll
  for (int bb = 0; bb < NBAND; ++bb) {
    unsigned long long m = __ballot(b == bb);
    if (lane == bb) wc[w][bb] = __popcll(m);
  }
  __syncthreads();
  if (tid < NBAND) {
    int s = 0;
#pragma unroll
    for (int w2 = 0; w2 < 16; ++w2) s += wc[w2][tid];
    cnt[blockIdx.x * NBAND + tid] = s;
  }
}

// ---------------- K2: scan block counts -> offsets; also init params + acc ----------------
__global__ void k2_scan(const int* __restrict__ cnt, int* __restrict__ boff,
                        Params* __restrict__ P, int nblk,
                        const float* __restrict__ lad, const float* __restrict__ lag,
                        const float* __restrict__ lkp, double* __restrict__ acc) {
  __shared__ int sd[1024];
  __shared__ int tot[NBAND], bstart[NBAND];
  int tid = threadIdx.x;
  if (tid == 0) {
    P->lags[0] = 0.f;
    P->amps[0] = 1.f;
    for (int j = 0; j < NBAND - 1; ++j) {
      P->lags[j + 1] = lag[j];
      P->amps[j + 1] = expf(lad[j]);
    }
    float a = expf(lkp[0]);
    float c = expf(lkp[1]);
    P->a = a;
    P->c = c;
    P->kphi1 = -c * 1.4426950408889634f;
    P->kphi2 = -2.f * c * 1.4426950408889634f;
    acc[0] = 0.0;
    acc[1] = 0.0;
  }
  int b = tid >> 7, seg = tid & 127;
  int per = nblk / 128;
  int blk0 = seg * per;
  int sum = 0;
  for (int u = 0; u < per; ++u) sum += cnt[(blk0 + u) * NBAND + b];
  int val = sum;
  sd[tid] = val;
  __syncthreads();
  for (int off = 1; off < 128; off <<= 1) {
    int yv = (seg >= off) ? sd[tid - off] : 0;
    __syncthreads();
    val += yv;
    sd[tid] = val;
    __syncthreads();
  }
  if (seg == 127) tot[b] = val;
  __syncthreads();
  if (tid == 0) {
    int g = 0;
    for (int bb = 0; bb < NBAND; ++bb) {
      bstart[bb] = g;
      P->bandstart[bb] = g;
      P->nb[bb] = tot[bb];
      g += tot[bb];
    }
    int s = 0;
    for (int bb = 0; bb < NBAND; ++bb) {
      P->blkbase[bb] = s;
      s += (tot[bb] + 255) / 256;
    }
    P->blkbase[NBAND] = s;
  }
  __syncthreads();
  int run = bstart[b] + (val - sum);
  for (int u = 0; u < per; ++u) {
    int idx = (blk0 + u) * NBAND + b;
    int x = cnt[idx];
    boff[idx] = run;
    run += x;
  }
}

// ---------------- K3: stable scatter of payload + packed keys into band partition ------
__global__ void k3_scatter(const float* __restrict__ t, const int* __restrict__ band,
                           const float* __restrict__ y, const float* __restrict__ dg,
                           const int* __restrict__ boff, const Params* __restrict__ P,
                           float4* __restrict__ payload, float* __restrict__ bt) {
  __shared__ int wc[16][NBAND];
  int tid = threadIdx.x;
  int i = blockIdx.x * K1_THREADS + tid;
  int b = band[i];
  float v = t[i] - P->lags[b];
  int lane = tid & 63, w = tid >> 6;
  int lower = 0;
#pragma unroll
  for (int bb = 0; bb < NBAND; ++bb) {
    unsigned long long m = __ballot(b == bb);
    if (lane == bb) wc[w][bb] = __popcll(m);
    if (b == bb) lower = __popcll(m & ((1ull << lane) - 1ull));
  }
  __syncthreads();
  int base = 0;
  for (int w2 = 0; w2 < w; ++w2) base += wc[w2][b];
  int pos = boff[blockIdx.x * NBAND + b] + base + lower;
  payload[pos] = make_float4(v, y[i], dg[i], P->amps[b]);
  bt[pos] = v;
}

// ---------------- K4a: cut table — value-linear splitters over global key range --------
// one thread per (boundary, band); cut = # keys in band strictly below splitter value.
__global__ void k4a_cuts(const float* __restrict__ bt, const Params* __restrict__ P,
                         int* __restrict__ cuts, int nout) {
  int s = blockIdx.x * 64 + threadIdx.x;
  if (s >= (nout + 1) * NBAND) return;
  int oo = s >> 3, b = s & 7;
  int res;
  if (oo == 0) res = 0;
  else if (oo == nout) res = P->nb[b];
  else {
    float vmin = bt[P->bandstart[0]];
    float vmax = bt[P->bandstart[0] + P->nb[0] - 1];
#pragma unroll
    for (int bb = 1; bb < NBAND; ++bb) {
      vmin = fminf(vmin, bt[P->bandstart[bb]]);
      vmax = fmaxf(vmax, bt[P->bandstart[bb] + P->nb[bb] - 1]);
    }
    float v = vmin + (float)((double)(vmax - vmin) * oo / nout);
    unsigned svu = f2u(v);
    const float* p = bt + P->bandstart[b];
    int lo = 0, hi = P->nb[b];
    while (lo < hi) {
      int mid = (lo + hi) >> 1;
      if (f2u(p[mid]) < svu) lo = mid + 1; else hi = mid;
    }
    res = lo;
  }
  cuts[oo * NBAND + b] = res;
}

// ---------------- K4: cooperative 8-way merge per contiguous output range -------------
__global__ __launch_bounds__(256) void k4_merge(const float* __restrict__ bt,
                                                const float4* __restrict__ payload,
                                                const Params* __restrict__ P,
                                                const int* __restrict__ cuts,
                                                float4* __restrict__ out4) {
  __shared__ unsigned long long bufA[MCAP];
  __shared__ unsigned long long bufB[MCAP];
  __shared__ int klo[NBAND], offs[NBAND + 1];
  __shared__ int sbs[NBAND];
  __shared__ long R0s;
  int tid = threadIdx.x;
  int o = blockIdx.x;
  if (tid < NBAND) sbs[tid] = P->bandstart[tid];
  if (tid == 0) {
    int s = 0;
    long r0 = 0;
    for (int b = 0; b < NBAND; ++b) {
      int lo = cuts[o * NBAND + b];
      int hi = cuts[(o + 1) * NBAND + b];
      klo[b] = lo;
      offs[b] = s;
      s += hi - lo;
      r0 += lo;
    }
    offs[NBAND] = s;
    R0s = r0;
  }
  __syncthreads();
  int M = offs[NBAND];
  if (M > MCAP) return;  // +20 sigma with value splitters; visible-failure guard
  int ro[NBAND + 1];
#pragma unroll
  for (int b = 0; b <= NBAND; ++b) ro[b] = offs[b];
  // --- stage records: (key:32 | band:3 | winpos:12)
  for (int p = tid; p < M; p += 256) {
    int b = 0;
#pragma unroll
    for (int bb = 1; bb < NBAND; ++bb) b += (p >= ro[bb]);
    int w = p - ro[b];
    unsigned u = f2u(bt[sbs[b] + klo[b] + w]);
    bufA[p] = ((unsigned long long)u << 15) | ((unsigned long long)b << 12) | (unsigned)w;
  }
  __syncthreads();
  // --- 3 rounds of pairwise merge-path
#pragma unroll
  for (int r = 0; r < 3; ++r) {
    const unsigned long long* src = (r == 1) ? bufB : bufA;
    unsigned long long* dst = (r == 1) ? bufA : bufB;
    int h = 1 << r;
    int tpm = 64 << r;               // threads per merge
    int mi = tid / tpm, tt = tid % tpm;
    int g = mi * 2 * h;
    int a1 = offs[g], a2 = offs[g + h], a3 = offs[g + 2 * h];
    int n1 = a2 - a1, n2 = a3 - a2;
    int total = n1 + n2;
    int e0 = (int)((long)tt * total / tpm);
    int e1 = (int)((long)(tt + 1) * total / tpm);
    int lo = max(0, e0 - n2), hi = min(e0, n1);
    while (lo < hi) {
      int mid = (lo + hi) >> 1;
      if (src[a1 + mid] < src[a2 + (e0 - mid) - 1]) lo = mid + 1; else hi = mid;
    }
    int i = lo, j = e0 - lo;
    unsigned long long x = (i < n1) ? src[a1 + i] : ~0ull;
    unsigned long long yv = (j < n2) ? src[a2 + j] : ~0ull;
    for (int k = e0; k < e1; ++k) {
      bool tk = x < yv;
      dst[a1 + k] = tk ? x : yv;
      if (tk) { ++i; x = (i < n1) ? src[a1 + i] : ~0ull; }
      else    { ++j; yv = (j < n2) ? src[a2 + j] : ~0ull; }
    }
    __syncthreads();
  }
  // --- emit: gather payload, coalesced contiguous output writes
  long R0 = R0s;
  for (int p = tid; p < M; p += 256) {
    unsigned long long rec = bufB[p];  // rounds: A->B, B->A, A->B => final in bufB
    int b = (int)((rec >> 12) & 7);
    int w = (int)(rec & 0xFFF);
    out4[R0 + p] = payload[sbs[b] + klo[b] + w];
  }
}

// ---------------- K5: chunked celerite scan with halo warm-up ----------------
struct ScanState {
  float Sp, fp, tprev, s1, s2;
};

template <bool ACCUM>
__device__ __forceinline__ void step_one(float4 v, ScanState& st, float a, float k1c,
                                         float k2c) {
  float t = v.x, yv = v.y, d = v.z, amp = v.w;
  float dt = t - st.tprev;
  st.tprev = t;
  float e2 = __builtin_amdgcn_exp2f(k2c * dt);  // phi^2
  float e1 = __builtin_amdgcn_exp2f(k1c * dt);  // phi
  float U = a * amp;
  float aa2 = U * amp;        // a*amp^2 = U*V
  float Aa = d + aa2;         // diagonal A
  float c1 = d - aa2;         // A - 2UV
  float V2 = amp * amp;
  float x = e2 * st.Sp;       // S_n
  float D = fmaf(-(U * U), x, Aa);
  float r = __builtin_amdgcn_rcpf(D);
  float num = fmaf(c1, x, V2);
  st.Sp = num * r;            // Moebius form of S + D*W^2
  float f = e1 * st.fp;
  float z = fmaf(-U, f, yv);
  float Wn = fmaf(-U, x, amp);  // V - U*S
  float W = Wn * r;
  st.fp = fmaf(W, z, f);
  if (ACCUM) {
    st.s1 = fmaf(z * z, r, st.s1);
    st.s2 += __builtin_amdgcn_logf(D);  // log2(D)
  }
}

template <bool ACCUM>
__device__ __forceinline__ void run_range(const float4* __restrict__ q, long s, long e,
                                          ScanState& st, float a, float k1c, float k2c) {
  float4 A[TILE], B[TILE];
#pragma unroll
  for (int u = 0; u < TILE; ++u) A[u] = q[s + u];
  for (long tb = s; tb < e; tb += 2 * TILE) {
#pragma unroll
    for (int u = 0; u < TILE; ++u) B[u] = q[tb + TILE + u];
#pragma unroll
    for (int u = 0; u < TILE; ++u) step_one<ACCUM>(A[u], st, a, k1c, k2c);
#pragma unroll
    for (int u = 0; u < TILE; ++u) A[u] = q[tb + 2 * TILE + u];  // prefetch next
#pragma unroll
    for (int u = 0; u < TILE; ++u) step_one<ACCUM>(B[u], st, a, k1c, k2c);
  }
}

__global__ __launch_bounds__(64, 1) void k5_scan(const float4* __restrict__ q,
                                                 const Params* __restrict__ P,
                                                 double* __restrict__ acc) {
  int k = blockIdx.x * 64 + threadIdx.x;
  long base = (long)k * CHUNK;
  float a = P->a, k1c = P->kphi1, k2c = P->kphi2;
  ScanState st;
  st.Sp = 0.f;
  st.fp = 0.f;
  st.s1 = 0.f;
  st.s2 = 0.f;
  long s0 = (k == 0) ? base : (base - HALO);
  st.tprev = q[s0].x;  // first dt = 0 (matches reference prepend for k==0)
  if (k > 0) run_range<false>(q, base - HALO, base, st, a, k1c, k2c);
  run_range<true>(q, base, base + CHUNK, st, a, k1c, k2c);
  float s1 = st.s1, s2 = st.s2;
#pragma unroll
  for (int off = 32; off > 0; off >>= 1) {
    s1 += __shfl_down(s1, off);
    s2 += __shfl_down(s2, off);
  }
  if (threadIdx.x == 0) {
    atomicAdd(&acc[0], (double)s1);
    atomicAdd(&acc[1], (double)s2);
  }
}

// ---------------- K6: finalize ----------------
__global__ void k6_final(const double* __restrict__ acc, float* __restrict__ out, long n) {
  double r = 0.5 * (acc[0] + acc[1] * 0.6931471805599453 +
                    (double)n * 1.8378770664093453);
  out[0] = (float)r;
}

extern "C" void kernel_launch(void* const* d_in, const int* in_sizes, int n_in,
                              void* d_out, int out_size, void* d_ws, size_t ws_size,
                              hipStream_t stream) {
  const float* t = (const float*)d_in[0];
  const int* band = (const int*)d_in[1];
  const float* y = (const float*)d_in[2];
  const float* dg = (const float*)d_in[3];
  const float* lad = (const float*)d_in[4];
  const float* lag = (const float*)d_in[5];
  const float* lkp = (const float*)d_in[6];
  float* out = (float*)d_out;
  long N = in_sizes[0];

  char* ws = (char*)d_ws;
  Params* P = (Params*)(ws + 0);
  double* acc = (double*)(ws + 1024);
  int* cnt = (int*)(ws + 8192);
  long nblk = N / K1_THREADS;  // 4096
  int* boff = (int*)(ws + 8192 + nblk * NBAND * 4);  // ends at 8192+2*131072=270336
  int nout = (int)(N / OUTBLK);  // 2048
  int* cuts = (int*)(ws + 294912);  // (nout+1)*8 ints = 65.6 KB, ends < 524288, no overlap
  // out4 first so k5's tail prefetch over-read lands inside payload (safe)
  float4* out4 = (float4*)(ws + 524288);
  float4* payload = (float4*)(ws + 524288 + (size_t)N * 16);
  float* bt = (float*)(ws + 524288 + (size_t)N * 32);
  // total ws need: 524288 + N*16 + N*16 + N*4  (~144.5 MB for N=4.19M)

  k1_hist<<<(int)nblk, K1_THREADS, 0, stream>>>(band, cnt);
  k2_scan<<<1, 1024, 0, stream>>>(cnt, boff, P, (int)nblk, lad, lag, lkp, acc);
  k3_scatter<<<(int)nblk, K1_THREADS, 0, stream>>>(t, band, y, dg, boff, P, payload, bt);
  int ncut = ((nout + 1) * NBAND + 63) / 64;
  k4a_cuts<<<ncut, 64, 0, stream>>>(bt, P, cuts, nout);
  k4_merge<<<nout, 256, 0, stream>>>(bt, payload, P, cuts, out4);
  long T = N / CHUNK;  // 32768 scan threads
  k5_scan<<<(int)(T / 64), 64, 0, stream>>>(out4, P, acc);
  k6_final<<<1, 1, 0, stream>>>(acc, out, N);
}

// Round 6
// 249.835 us; speedup vs baseline: 2.2801x; 1.1973x over previous
//
#include <hip/hip_runtime.h>
#include <hip/hip_bf16.h>
#include <math.h>

#define NBAND 8
#define K1_THREADS 1024
#define CHUNK 128
#define HALO  192
#define TILE  16
#define OUTBLK 2048          // merged outputs per k4 block (mean)
#define MCAP   3072          // LDS record capacity (mean 2048, +20 sigma safe)
#define SEG    32            // k1-blocks per scan segment
#define NSEG   128           // nblk / SEG

struct Params {
  float lags[NBAND];
  float amps[NBAND];
  float a, c, kphi1, kphi2;
  int bandstart[NBAND];
  int nb[NBAND];
  int blkbase[NBAND + 1];
};

__device__ __forceinline__ unsigned f2u(float f) {
  unsigned b = __float_as_uint(f);
  return b ^ ((b >> 31) ? 0xFFFFFFFFu : 0x80000000u);
}

// ---------------- K1: per-block band histogram (ballot, no atomics) ----------------
__global__ void k1_hist(const int* __restrict__ band, int* __restrict__ cnt) {
  __shared__ int wc[16][NBAND];
  int tid = threadIdx.x;
  int i = blockIdx.x * K1_THREADS + tid;
  int b = band[i];
  int lane = tid & 63, w = tid >> 6;
#pragma unroll
  for (int bb = 0; bb < NBAND; ++bb) {
    unsigned long long m = __ballot(b == bb);
    if (lane == bb) wc[w][bb] = __popcll(m);
  }
  __syncthreads();
  if (tid < NBAND) {
    int s = 0;
#pragma unroll
    for (int w2 = 0; w2 < 16; ++w2) s += wc[w2][tid];
    cnt[blockIdx.x * NBAND + tid] = s;
  }
}

// ---------------- K2a: per-(segment, band) partial sums (grid-parallel) ----------------
__global__ void k2a_segsum(const int* __restrict__ cnt, int* __restrict__ segsum) {
  int s = blockIdx.x * 256 + threadIdx.x;  // s = seg*8 + b
  if (s >= NSEG * NBAND) return;
  int b = s & 7, seg = s >> 3;
  int base = seg * SEG;
  int sum = 0;
#pragma unroll 8
  for (int u = 0; u < SEG; ++u) sum += cnt[(base + u) * NBAND + b];
  segsum[s] = sum;
}

// ---------------- K2b: scan segment sums; params + acc init; write segbase ------------
__global__ void k2b_scan(const int* __restrict__ segsum, int* __restrict__ segbase,
                         Params* __restrict__ P,
                         const float* __restrict__ lad, const float* __restrict__ lag,
                         const float* __restrict__ lkp, double* __restrict__ acc) {
  __shared__ int sd[NSEG * NBAND];
  __shared__ int tot[NBAND], bstart[NBAND];
  int tid = threadIdx.x;  // 1024 = NSEG*NBAND; s = seg*8 + b
  if (tid == 0) {
    P->lags[0] = 0.f;
    P->amps[0] = 1.f;
    for (int j = 0; j < NBAND - 1; ++j) {
      P->lags[j + 1] = lag[j];
      P->amps[j + 1] = expf(lad[j]);
    }
    float a = expf(lkp[0]);
    float c = expf(lkp[1]);
    P->a = a;
    P->c = c;
    P->kphi1 = -c * 1.4426950408889634f;
    P->kphi2 = -2.f * c * 1.4426950408889634f;
    acc[0] = 0.0;
    acc[1] = 0.0;
  }
  int b = tid & 7, seg = tid >> 3;
  int sum = segsum[tid];
  int val = sum;
  sd[tid] = val;
  __syncthreads();
  for (int off = 1; off < NSEG; off <<= 1) {
    int yv = (seg >= off) ? sd[tid - off * NBAND] : 0;
    __syncthreads();
    val += yv;
    sd[tid] = val;
    __syncthreads();
  }
  if (seg == NSEG - 1) tot[b] = val;
  __syncthreads();
  if (tid == 0) {
    int g = 0;
    for (int bb = 0; bb < NBAND; ++bb) {
      bstart[bb] = g;
      P->bandstart[bb] = g;
      P->nb[bb] = tot[bb];
      g += tot[bb];
    }
    int s = 0;
    for (int bb = 0; bb < NBAND; ++bb) {
      P->blkbase[bb] = s;
      s += (tot[bb] + 255) / 256;
    }
    P->blkbase[NBAND] = s;
  }
  __syncthreads();
  segbase[tid] = bstart[b] + (val - sum);  // exclusive prefix of earlier segments
}

// ---------------- K2c: expand segment bases to per-(block, band) offsets ---------------
__global__ void k2c_boff(const int* __restrict__ cnt, const int* __restrict__ segbase,
                         int* __restrict__ boff) {
  int s = blockIdx.x * 256 + threadIdx.x;  // s = seg*8 + b
  if (s >= NSEG * NBAND) return;
  int b = s & 7, seg = s >> 3;
  int base = seg * SEG;
  int run = segbase[s];
  for (int u = 0; u < SEG; ++u) {
    int idx = (base + u) * NBAND + b;
    int x = cnt[idx];
    boff[idx] = run;
    run += x;
  }
}

// ---------------- K3: stable scatter of payload + packed keys into band partition ------
__global__ void k3_scatter(const float* __restrict__ t, const int* __restrict__ band,
                           const float* __restrict__ y, const float* __restrict__ dg,
                           const int* __restrict__ boff, const Params* __restrict__ P,
                           float4* __restrict__ payload, float* __restrict__ bt) {
  __shared__ int wc[16][NBAND];
  int tid = threadIdx.x;
  int i = blockIdx.x * K1_THREADS + tid;
  int b = band[i];
  float v = t[i] - P->lags[b];
  int lane = tid & 63, w = tid >> 6;
  int lower = 0;
#pragma unroll
  for (int bb = 0; bb < NBAND; ++bb) {
    unsigned long long m = __ballot(b == bb);
    if (lane == bb) wc[w][bb] = __popcll(m);
    if (b == bb) lower = __popcll(m & ((1ull << lane) - 1ull));
  }
  __syncthreads();
  int base = 0;
  for (int w2 = 0; w2 < w; ++w2) base += wc[w2][b];
  int pos = boff[blockIdx.x * NBAND + b] + base + lower;
  payload[pos] = make_float4(v, y[i], dg[i], P->amps[b]);
  bt[pos] = v;
}

// ---------------- K4a: cut table — value-linear splitters over global key range --------
__global__ void k4a_cuts(const float* __restrict__ bt, const Params* __restrict__ P,
                         int* __restrict__ cuts, int nout) {
  int s = blockIdx.x * 64 + threadIdx.x;
  if (s >= (nout + 1) * NBAND) return;
  int oo = s >> 3, b = s & 7;
  int res;
  if (oo == 0) res = 0;
  else if (oo == nout) res = P->nb[b];
  else {
    float vmin = bt[P->bandstart[0]];
    float vmax = bt[P->bandstart[0] + P->nb[0] - 1];
#pragma unroll
    for (int bb = 1; bb < NBAND; ++bb) {
      vmin = fminf(vmin, bt[P->bandstart[bb]]);
      vmax = fmaxf(vmax, bt[P->bandstart[bb] + P->nb[bb] - 1]);
    }
    float v = vmin + (float)((double)(vmax - vmin) * oo / nout);
    unsigned svu = f2u(v);
    const float* p = bt + P->bandstart[b];
    int lo = 0, hi = P->nb[b];
    while (lo < hi) {
      int mid = (lo + hi) >> 1;
      if (f2u(p[mid]) < svu) lo = mid + 1; else hi = mid;
    }
    res = lo;
  }
  cuts[oo * NBAND + b] = res;
}

// ---------------- K4: cooperative 8-way merge per contiguous output range -------------
__global__ __launch_bounds__(256) void k4_merge(const float* __restrict__ bt,
                                                const float4* __restrict__ payload,
                                                const Params* __restrict__ P,
                                                const int* __restrict__ cuts,
                                                float4* __restrict__ out4) {
  __shared__ unsigned long long bufA[MCAP];
  __shared__ unsigned long long bufB[MCAP];
  __shared__ int klo[NBAND], offs[NBAND + 1];
  __shared__ int sbs[NBAND];
  __shared__ long R0s;
  int tid = threadIdx.x;
  int o = blockIdx.x;
  if (tid < NBAND) sbs[tid] = P->bandstart[tid];
  if (tid == 0) {
    int s = 0;
    long r0 = 0;
    for (int b = 0; b < NBAND; ++b) {
      int lo = cuts[o * NBAND + b];
      int hi = cuts[(o + 1) * NBAND + b];
      klo[b] = lo;
      offs[b] = s;
      s += hi - lo;
      r0 += lo;
    }
    offs[NBAND] = s;
    R0s = r0;
  }
  __syncthreads();
  int M = offs[NBAND];
  if (M > MCAP) return;  // +20 sigma with value splitters; visible-failure guard
  int ro[NBAND + 1];
#pragma unroll
  for (int b = 0; b <= NBAND; ++b) ro[b] = offs[b];
  // --- stage records: (key:32 | band:3 | winpos:12)
  for (int p = tid; p < M; p += 256) {
    int b = 0;
#pragma unroll
    for (int bb = 1; bb < NBAND; ++bb) b += (p >= ro[bb]);
    int w = p - ro[b];
    unsigned u = f2u(bt[sbs[b] + klo[b] + w]);
    bufA[p] = ((unsigned long long)u << 15) | ((unsigned long long)b << 12) | (unsigned)w;
  }
  __syncthreads();
  // --- 3 rounds of pairwise merge-path
#pragma unroll
  for (int r = 0; r < 3; ++r) {
    const unsigned long long* src = (r == 1) ? bufB : bufA;
    unsigned long long* dst = (r == 1) ? bufA : bufB;
    int h = 1 << r;
    int tpm = 64 << r;               // threads per merge
    int mi = tid / tpm, tt = tid % tpm;
    int g = mi * 2 * h;
    int a1 = offs[g], a2 = offs[g + h], a3 = offs[g + 2 * h];
    int n1 = a2 - a1, n2 = a3 - a2;
    int total = n1 + n2;
    int e0 = (int)((long)tt * total / tpm);
    int e1 = (int)((long)(tt + 1) * total / tpm);
    int lo = max(0, e0 - n2), hi = min(e0, n1);
    while (lo < hi) {
      int mid = (lo + hi) >> 1;
      if (src[a1 + mid] < src[a2 + (e0 - mid) - 1]) lo = mid + 1; else hi = mid;
    }
    int i = lo, j = e0 - lo;
    unsigned long long x = (i < n1) ? src[a1 + i] : ~0ull;
    unsigned long long yv = (j < n2) ? src[a2 + j] : ~0ull;
    for (int k = e0; k < e1; ++k) {
      bool tk = x < yv;
      dst[a1 + k] = tk ? x : yv;
      if (tk) { ++i; x = (i < n1) ? src[a1 + i] : ~0ull; }
      else    { ++j; yv = (j < n2) ? src[a2 + j] : ~0ull; }
    }
    __syncthreads();
  }
  // --- emit: gather payload, coalesced contiguous output writes
  long R0 = R0s;
  for (int p = tid; p < M; p += 256) {
    unsigned long long rec = bufB[p];  // rounds: A->B, B->A, A->B => final in bufB
    int b = (int)((rec >> 12) & 7);
    int w = (int)(rec & 0xFFF);
    out4[R0 + p] = payload[sbs[b] + klo[b] + w];
  }
}

// ---------------- K5: chunked celerite scan with halo warm-up ----------------
struct ScanState {
  float Sp, fp, tprev, s1, s2;
};

template <bool ACCUM>
__device__ __forceinline__ void step_one(float4 v, ScanState& st, float a, float k1c,
                                         float k2c) {
  float t = v.x, yv = v.y, d = v.z, amp = v.w;
  float dt = t - st.tprev;
  st.tprev = t;
  float e2 = __builtin_amdgcn_exp2f(k2c * dt);  // phi^2
  float e1 = __builtin_amdgcn_exp2f(k1c * dt);  // phi
  float U = a * amp;
  float aa2 = U * amp;        // a*amp^2 = U*V
  float Aa = d + aa2;         // diagonal A
  float c1 = d - aa2;         // A - 2UV
  float V2 = amp * amp;
  float x = e2 * st.Sp;       // S_n
  float D = fmaf(-(U * U), x, Aa);
  float r = __builtin_amdgcn_rcpf(D);
  float num = fmaf(c1, x, V2);
  st.Sp = num * r;            // Moebius form of S + D*W^2
  float f = e1 * st.fp;
  float z = fmaf(-U, f, yv);
  float Wn = fmaf(-U, x, amp);  // V - U*S
  float W = Wn * r;
  st.fp = fmaf(W, z, f);
  if (ACCUM) {
    st.s1 = fmaf(z * z, r, st.s1);
    st.s2 += __builtin_amdgcn_logf(D);  // log2(D)
  }
}

template <bool ACCUM>
__device__ __forceinline__ void run_range(const float4* __restrict__ q, long s, long e,
                                          ScanState& st, float a, float k1c, float k2c) {
  float4 A[TILE], B[TILE];
#pragma unroll
  for (int u = 0; u < TILE; ++u) A[u] = q[s + u];
  for (long tb = s; tb < e; tb += 2 * TILE) {
#pragma unroll
    for (int u = 0; u < TILE; ++u) B[u] = q[tb + TILE + u];
#pragma unroll
    for (int u = 0; u < TILE; ++u) step_one<ACCUM>(A[u], st, a, k1c, k2c);
#pragma unroll
    for (int u = 0; u < TILE; ++u) A[u] = q[tb + 2 * TILE + u];  // prefetch next
#pragma unroll
    for (int u = 0; u < TILE; ++u) step_one<ACCUM>(B[u], st, a, k1c, k2c);
  }
}

__global__ __launch_bounds__(64, 1) void k5_scan(const float4* __restrict__ q,
                                                 const Params* __restrict__ P,
                                                 double* __restrict__ acc) {
  int k = blockIdx.x * 64 + threadIdx.x;
  long base = (long)k * CHUNK;
  float a = P->a, k1c = P->kphi1, k2c = P->kphi2;
  ScanState st;
  st.Sp = 0.f;
  st.fp = 0.f;
  st.s1 = 0.f;
  st.s2 = 0.f;
  long s0 = (k == 0) ? base : (base - HALO);
  st.tprev = q[s0].x;  // first dt = 0 (matches reference prepend for k==0)
  if (k > 0) run_range<false>(q, base - HALO, base, st, a, k1c, k2c);
  run_range<true>(q, base, base + CHUNK, st, a, k1c, k2c);
  float s1 = st.s1, s2 = st.s2;
#pragma unroll
  for (int off = 32; off > 0; off >>= 1) {
    s1 += __shfl_down(s1, off);
    s2 += __shfl_down(s2, off);
  }
  if (threadIdx.x == 0) {
    atomicAdd(&acc[0], (double)s1);
    atomicAdd(&acc[1], (double)s2);
  }
}

// ---------------- K6: finalize ----------------
__global__ void k6_final(const double* __restrict__ acc, float* __restrict__ out, long n) {
  double r = 0.5 * (acc[0] + acc[1] * 0.6931471805599453 +
                    (double)n * 1.8378770664093453);
  out[0] = (float)r;
}

extern "C" void kernel_launch(void* const* d_in, const int* in_sizes, int n_in,
                              void* d_out, int out_size, void* d_ws, size_t ws_size,
                              hipStream_t stream) {
  const float* t = (const float*)d_in[0];
  const int* band = (const int*)d_in[1];
  const float* y = (const float*)d_in[2];
  const float* dg = (const float*)d_in[3];
  const float* lad = (const float*)d_in[4];
  const float* lag = (const float*)d_in[5];
  const float* lkp = (const float*)d_in[6];
  float* out = (float*)d_out;
  long N = in_sizes[0];

  char* ws = (char*)d_ws;
  Params* P = (Params*)(ws + 0);
  double* acc = (double*)(ws + 1024);
  int* cnt = (int*)(ws + 8192);
  long nblk = N / K1_THREADS;  // 4096
  int* boff = (int*)(ws + 8192 + nblk * NBAND * 4);  // ends at 270336
  int* segsum = (int*)(ws + 270336);   // NSEG*NBAND ints = 4 KB
  int* segbase = (int*)(ws + 274432);  // NSEG*NBAND ints = 4 KB
  int nout = (int)(N / OUTBLK);  // 2048
  int* cuts = (int*)(ws + 294912);  // (nout+1)*8 ints = 65.6 KB, ends < 524288
  // out4 first so k5's tail prefetch over-read lands inside payload (safe)
  float4* out4 = (float4*)(ws + 524288);
  float4* payload = (float4*)(ws + 524288 + (size_t)N * 16);
  float* bt = (float*)(ws + 524288 + (size_t)N * 32);
  // total ws need: 524288 + N*16 + N*16 + N*4  (~144.5 MB for N=4.19M)

  k1_hist<<<(int)nblk, K1_THREADS, 0, stream>>>(band, cnt);
  k2a_segsum<<<(NSEG * NBAND + 255) / 256, 256, 0, stream>>>(cnt, segsum);
  k2b_scan<<<1, NSEG * NBAND, 0, stream>>>(segsum, segbase, P, lad, lag, lkp, acc);
  k2c_boff<<<(NSEG * NBAND + 255) / 256, 256, 0, stream>>>(cnt, segbase, boff);
  k3_scatter<<<(int)nblk, K1_THREADS, 0, stream>>>(t, band, y, dg, boff, P, payload, bt);
  int ncut = ((nout + 1) * NBAND + 63) / 64;
  k4a_cuts<<<ncut, 64, 0, stream>>>(bt, P, cuts, nout);
  k4_merge<<<nout, 256, 0, stream>>>(bt, payload, P, cuts, out4);
  long T = N / CHUNK;  // 32768 scan threads
  k5_scan<<<(int)(T / 64), 64, 0, stream>>>(out4, P, acc);
  k6_final<<<1, 1, 0, stream>>>(acc, out, N);
}

// Round 7
// 201.266 us; speedup vs baseline: 2.8304x; 1.2413x over previous
//
#include <hip/hip_runtime.h>
#include <hip/hip_bf16.h>
#include <hip/hip_fp16.h>
#include <math.h>

#define NBAND 8
#define K1_THREADS 1024
#define CHUNK 128
#define HALO  128
#define TILE  16
#define OUTBLK 2048          // merged outputs per k4 block (mean)
#define MCAP   2432          // LDS record capacity (mean 2048, sd~45 -> +8.5 sigma)
#define SEG    32            // k1-blocks per scan segment
#define NSEG   128           // nblk / SEG
#define NPART  512           // k5 blocks (N/CHUNK/64)

struct Params {
  float lags[NBAND];
  float amps[NBAND];
  float inv_amp[NBAND];
  float inv_amp2[NBAND];
  float a, c, kphi1, kphi2;
  int bandstart[NBAND];
  int nb[NBAND];
  int blkbase[NBAND + 1];
};

__device__ __forceinline__ unsigned f2u(float f) {
  unsigned b = __float_as_uint(f);
  return b ^ ((b >> 31) ? 0xFFFFFFFFu : 0x80000000u);
}
__device__ __forceinline__ float u2f(unsigned u) {
  unsigned m = (u & 0x80000000u) ? 0x80000000u : 0xFFFFFFFFu;
  return __uint_as_float(u ^ m);
}

// ---------------- K1: per-block band histogram (ballot, no atomics) ----------------
__global__ void k1_hist(const int* __restrict__ band, int* __restrict__ cnt) {
  __shared__ int wc[16][NBAND];
  int tid = threadIdx.x;
  int i = blockIdx.x * K1_THREADS + tid;
  int b = band[i];
  int lane = tid & 63, w = tid >> 6;
#pragma unroll
  for (int bb = 0; bb < NBAND; ++bb) {
    unsigned long long m = __ballot(b == bb);
    if (lane == bb) wc[w][bb] = __popcll(m);
  }
  __syncthreads();
  if (tid < NBAND) {
    int s = 0;
#pragma unroll
    for (int w2 = 0; w2 < 16; ++w2) s += wc[w2][tid];
    cnt[blockIdx.x * NBAND + tid] = s;
  }
}

// ---------------- K2a: per-(segment, band) partial sums (grid-parallel) ----------------
__global__ void k2a_segsum(const int* __restrict__ cnt, int* __restrict__ segsum) {
  int s = blockIdx.x * 256 + threadIdx.x;  // s = seg*8 + b
  if (s >= NSEG * NBAND) return;
  int b = s & 7, seg = s >> 3;
  int base = seg * SEG;
  int sum = 0;
#pragma unroll 8
  for (int u = 0; u < SEG; ++u) sum += cnt[(base + u) * NBAND + b];
  segsum[s] = sum;
}

// ---------------- K2b: scan segment sums; params init; write segbase ------------------
__global__ void k2b_scan(const int* __restrict__ segsum, int* __restrict__ segbase,
                         Params* __restrict__ P,
                         const float* __restrict__ lad, const float* __restrict__ lag,
                         const float* __restrict__ lkp) {
  __shared__ int sd[NSEG * NBAND];
  __shared__ int tot[NBAND], bstart[NBAND];
  int tid = threadIdx.x;  // 1024 = NSEG*NBAND; s = seg*8 + b
  if (tid == 0) {
    P->lags[0] = 0.f;
    P->amps[0] = 1.f;
    P->inv_amp[0] = 1.f;
    P->inv_amp2[0] = 1.f;
    for (int j = 0; j < NBAND - 1; ++j) {
      P->lags[j + 1] = lag[j];
      float am = expf(lad[j]);
      P->amps[j + 1] = am;
      float ia = expf(-lad[j]);
      P->inv_amp[j + 1] = ia;
      P->inv_amp2[j + 1] = ia * ia;
    }
    float a = expf(lkp[0]);
    float c = expf(lkp[1]);
    P->a = a;
    P->c = c;
    P->kphi1 = -c * 1.4426950408889634f;
    P->kphi2 = -2.f * c * 1.4426950408889634f;
  }
  int b = tid & 7, seg = tid >> 3;
  int sum = segsum[tid];
  int val = sum;
  sd[tid] = val;
  __syncthreads();
  for (int off = 1; off < NSEG; off <<= 1) {
    int yv = (seg >= off) ? sd[tid - off * NBAND] : 0;
    __syncthreads();
    val += yv;
    sd[tid] = val;
    __syncthreads();
  }
  if (seg == NSEG - 1) tot[b] = val;
  __syncthreads();
  if (tid == 0) {
    int g = 0;
    for (int bb = 0; bb < NBAND; ++bb) {
      bstart[bb] = g;
      P->bandstart[bb] = g;
      P->nb[bb] = tot[bb];
      g += tot[bb];
    }
    int s = 0;
    for (int bb = 0; bb < NBAND; ++bb) {
      P->blkbase[bb] = s;
      s += (tot[bb] + 255) / 256;
    }
    P->blkbase[NBAND] = s;
  }
  __syncthreads();
  segbase[tid] = bstart[b] + (val - sum);  // exclusive prefix of earlier segments
}

// ---------------- K2c: expand segment bases to per-(block, band) offsets ---------------
__global__ void k2c_boff(const int* __restrict__ cnt, const int* __restrict__ segbase,
                         int* __restrict__ boff) {
  int s = blockIdx.x * 256 + threadIdx.x;  // s = seg*8 + b
  if (s >= NSEG * NBAND) return;
  int b = s & 7, seg = s >> 3;
  int base = seg * SEG;
  int run = segbase[s];
  for (int u = 0; u < SEG; ++u) {
    int idx = (base + u) * NBAND + b;
    int x = cnt[idx];
    boff[idx] = run;
    run += x;
  }
}

// ---------------- K3: stable scatter of keys + packed (y', d') into band partition ------
// amp-normalized: y' = y/amp_b, d' = d/amp_b^2; packed as (bf16 y' << 16) | fp16 d'.
__global__ void k3_scatter(const float* __restrict__ t, const int* __restrict__ band,
                           const float* __restrict__ y, const float* __restrict__ dg,
                           const int* __restrict__ boff, const Params* __restrict__ P,
                           unsigned* __restrict__ pay2, float* __restrict__ bt) {
  __shared__ int wc[16][NBAND];
  int tid = threadIdx.x;
  int i = blockIdx.x * K1_THREADS + tid;
  int b = band[i];
  float v = t[i] - P->lags[b];
  int lane = tid & 63, w = tid >> 6;
  int lower = 0;
#pragma unroll
  for (int bb = 0; bb < NBAND; ++bb) {
    unsigned long long m = __ballot(b == bb);
    if (lane == bb) wc[w][bb] = __popcll(m);
    if (b == bb) lower = __popcll(m & ((1ull << lane) - 1ull));
  }
  __syncthreads();
  int base = 0;
  for (int w2 = 0; w2 < w; ++w2) base += wc[w2][b];
  int pos = boff[blockIdx.x * NBAND + b] + base + lower;
  float yp = y[i] * P->inv_amp[b];
  float dp = dg[i] * P->inv_amp2[b];
  unsigned yx = __float_as_uint(yp);
  unsigned yb = (yx + 0x7FFFu + ((yx >> 16) & 1u)) >> 16;      // bf16 RNE
  unsigned db = (unsigned)__half_as_ushort(__float2half(dp));  // fp16 RNE
  pay2[pos] = (yb << 16) | db;
  bt[pos] = v;
}

// ---------------- K4a: cut table — value-linear splitters over global key range --------
__global__ void k4a_cuts(const float* __restrict__ bt, const Params* __restrict__ P,
                         int* __restrict__ cuts, int nout) {
  int s = blockIdx.x * 64 + threadIdx.x;
  if (s >= (nout + 1) * NBAND) return;
  int oo = s >> 3, b = s & 7;
  int res;
  if (oo == 0) res = 0;
  else if (oo == nout) res = P->nb[b];
  else {
    float vmin = bt[P->bandstart[0]];
    float vmax = bt[P->bandstart[0] + P->nb[0] - 1];
#pragma unroll
    for (int bb = 1; bb < NBAND; ++bb) {
      vmin = fminf(vmin, bt[P->bandstart[bb]]);
      vmax = fmaxf(vmax, bt[P->bandstart[bb] + P->nb[bb] - 1]);
    }
    float v = vmin + (float)((double)(vmax - vmin) * oo / nout);
    unsigned svu = f2u(v);
    const float* p = bt + P->bandstart[b];
    int lo = 0, hi = P->nb[b];
    while (lo < hi) {
      int mid = (lo + hi) >> 1;
      if (f2u(p[mid]) < svu) lo = mid + 1; else hi = mid;
    }
    res = lo;
  }
  cuts[oo * NBAND + b] = res;
}

// ---------------- K4: cooperative 8-way merge per contiguous output range -------------
__global__ __launch_bounds__(256) void k4_merge(const float* __restrict__ bt,
                                                const unsigned* __restrict__ pay2,
                                                const Params* __restrict__ P,
                                                const int* __restrict__ cuts,
                                                float2* __restrict__ out8) {
  __shared__ unsigned long long bufA[MCAP];
  __shared__ unsigned long long bufB[MCAP];
  __shared__ int klo[NBAND], offs[NBAND + 1];
  __shared__ int sbs[NBAND];
  __shared__ long R0s;
  int tid = threadIdx.x;
  int o = blockIdx.x;
  if (tid < NBAND) sbs[tid] = P->bandstart[tid];
  if (tid == 0) {
    int s = 0;
    long r0 = 0;
    for (int b = 0; b < NBAND; ++b) {
      int lo = cuts[o * NBAND + b];
      int hi = cuts[(o + 1) * NBAND + b];
      klo[b] = lo;
      offs[b] = s;
      s += hi - lo;
      r0 += lo;
    }
    offs[NBAND] = s;
    R0s = r0;
  }
  __syncthreads();
  int M = offs[NBAND];
  if (M > MCAP) return;  // far beyond +8 sigma; visible-failure guard
  int ro[NBAND + 1];
#pragma unroll
  for (int b = 0; b <= NBAND; ++b) ro[b] = offs[b];
  // --- stage records: (key:32 | band:3 | winpos:12)
  for (int p = tid; p < M; p += 256) {
    int b = 0;
#pragma unroll
    for (int bb = 1; bb < NBAND; ++bb) b += (p >= ro[bb]);
    int w = p - ro[b];
    unsigned u = f2u(bt[sbs[b] + klo[b] + w]);
    bufA[p] = ((unsigned long long)u << 15) | ((unsigned long long)b << 12) | (unsigned)w;
  }
  __syncthreads();
  // --- 3 rounds of pairwise merge-path
#pragma unroll
  for (int r = 0; r < 3; ++r) {
    const unsigned long long* src = (r == 1) ? bufB : bufA;
    unsigned long long* dst = (r == 1) ? bufA : bufB;
    int h = 1 << r;
    int tpm = 64 << r;               // threads per merge
    int mi = tid / tpm, tt = tid % tpm;
    int g = mi * 2 * h;
    int a1 = offs[g], a2 = offs[g + h], a3 = offs[g + 2 * h];
    int n1 = a2 - a1, n2 = a3 - a2;
    int total = n1 + n2;
    int e0 = (int)((long)tt * total / tpm);
    int e1 = (int)((long)(tt + 1) * total / tpm);
    int lo = max(0, e0 - n2), hi = min(e0, n1);
    while (lo < hi) {
      int mid = (lo + hi) >> 1;
      if (src[a1 + mid] < src[a2 + (e0 - mid) - 1]) lo = mid + 1; else hi = mid;
    }
    int i = lo, j = e0 - lo;
    unsigned long long x = (i < n1) ? src[a1 + i] : ~0ull;
    unsigned long long yv = (j < n2) ? src[a2 + j] : ~0ull;
    for (int k = e0; k < e1; ++k) {
      bool tk = x < yv;
      dst[a1 + k] = tk ? x : yv;
      if (tk) { ++i; x = (i < n1) ? src[a1 + i] : ~0ull; }
      else    { ++j; yv = (j < n2) ? src[a2 + j] : ~0ull; }
    }
    __syncthreads();
  }
  // --- emit: gather 4B payload, coalesced 8B contiguous output writes
  long R0 = R0s;
  for (int p = tid; p < M; p += 256) {
    unsigned long long rec = bufB[p];  // rounds: A->B, B->A, A->B => final in bufB
    int b = (int)((rec >> 12) & 7);
    int w = (int)(rec & 0xFFF);
    unsigned key = (unsigned)(rec >> 15);
    unsigned pv = pay2[sbs[b] + klo[b] + w];
    out8[R0 + p] = make_float2(u2f(key), __uint_as_float(pv));
  }
}

// ---------------- K5: chunked celerite scan (uniform amp), halo warm-up ----------------
struct ScanState {
  float Sp, fp, tprev, s1, s2;
};

template <bool ACCUM>
__device__ __forceinline__ void step_one(float2 v, ScanState& st, float a, float a2,
                                         float k1c, float k2c) {
  float t = v.x;
  unsigned pv = __float_as_uint(v.y);
  float yv = __uint_as_float(pv & 0xFFFF0000u);                       // bf16 y'
  float d = __half2float(__ushort_as_half((unsigned short)(pv & 0xFFFFu)));  // fp16 d'
  float dt = t - st.tprev;
  st.tprev = t;
  float e2 = __builtin_amdgcn_exp2f(k2c * dt);  // phi^2
  float e1 = __builtin_amdgcn_exp2f(k1c * dt);  // phi
  float Aa = d + a;           // diagonal A (U=a, V=1)
  float c1 = d - a;           // A - 2UV
  float x = e2 * st.Sp;       // S_n
  float D = fmaf(-a2, x, Aa);
  float r = __builtin_amdgcn_rcpf(D);
  float num = fmaf(c1, x, 1.0f);
  st.Sp = num * r;            // Moebius form of S + D*W^2
  float f = e1 * st.fp;
  float z = fmaf(-a, f, yv);
  float Wn = fmaf(-a, x, 1.0f);  // V - U*S
  float W = Wn * r;
  st.fp = fmaf(W, z, f);
  if (ACCUM) {
    st.s1 = fmaf(z * z, r, st.s1);
    st.s2 += __builtin_amdgcn_logf(D);  // log2(D)
  }
}

template <bool ACCUM>
__device__ __forceinline__ void run_range(const float2* __restrict__ q, long s, long e,
                                          ScanState& st, float a, float a2, float k1c,
                                          float k2c) {
  float2 A[TILE], B[TILE];
#pragma unroll
  for (int u = 0; u < TILE; ++u) A[u] = q[s + u];
  for (long tb = s; tb < e; tb += 2 * TILE) {
#pragma unroll
    for (int u = 0; u < TILE; ++u) B[u] = q[tb + TILE + u];
#pragma unroll
    for (int u = 0; u < TILE; ++u) step_one<ACCUM>(A[u], st, a, a2, k1c, k2c);
#pragma unroll
    for (int u = 0; u < TILE; ++u) A[u] = q[tb + 2 * TILE + u];  // prefetch next
#pragma unroll
    for (int u = 0; u < TILE; ++u) step_one<ACCUM>(B[u], st, a, a2, k1c, k2c);
  }
}

__global__ __launch_bounds__(64, 1) void k5_scan(const float2* __restrict__ q,
                                                 const Params* __restrict__ P,
                                                 double2* __restrict__ part) {
  int k = blockIdx.x * 64 + threadIdx.x;
  long base = (long)k * CHUNK;
  float a = P->a, a2 = a * a, k1c = P->kphi1, k2c = P->kphi2;
  ScanState st;
  st.Sp = 0.f;
  st.fp = 0.f;
  st.s1 = 0.f;
  st.s2 = 0.f;
  long s0 = (k == 0) ? base : (base - HALO);
  st.tprev = q[s0].x;  // first dt = 0 (matches reference prepend for k==0)
  if (k > 0) run_range<false>(q, base - HALO, base, st, a, a2, k1c, k2c);
  run_range<true>(q, base, base + CHUNK, st, a, a2, k1c, k2c);
  float s1 = st.s1, s2 = st.s2;
#pragma unroll
  for (int off = 32; off > 0; off >>= 1) {
    s1 += __shfl_down(s1, off);
    s2 += __shfl_down(s2, off);
  }
  if (threadIdx.x == 0) part[blockIdx.x] = make_double2((double)s1, (double)s2);
}

// ---------------- K6: reduce partials + amp-normalization correction ----------------
__global__ void k6_final(const double2* __restrict__ part, const Params* __restrict__ P,
                         const float* __restrict__ lad, float* __restrict__ out, long n) {
  int tid = threadIdx.x;  // 64
  double s1 = 0.0, s2 = 0.0;
  for (int u = tid; u < NPART; u += 64) {
    double2 p = part[u];
    s1 += p.x;
    s2 += p.y;
  }
#pragma unroll
  for (int off = 32; off > 0; off >>= 1) {
    s1 += __shfl_down(s1, off);
    s2 += __shfl_down(s2, off);
  }
  if (tid == 0) {
    double ampc = 0.0;  // sum_i log amp_i = sum_b n_b * log_amp_b
    for (int b = 1; b < NBAND; ++b) ampc += (double)P->nb[b] * (double)lad[b - 1];
    double r = 0.5 * (s1 + s2 * 0.6931471805599453 + (double)n * 1.8378770664093453)
               + ampc;
    out[0] = (float)r;
  }
}

extern "C" void kernel_launch(void* const* d_in, const int* in_sizes, int n_in,
                              void* d_out, int out_size, void* d_ws, size_t ws_size,
                              hipStream_t stream) {
  const float* t = (const float*)d_in[0];
  const int* band = (const int*)d_in[1];
  const float* y = (const float*)d_in[2];
  const float* dg = (const float*)d_in[3];
  const float* lad = (const float*)d_in[4];
  const float* lag = (const float*)d_in[5];
  const float* lkp = (const float*)d_in[6];
  float* out = (float*)d_out;
  long N = in_sizes[0];

  char* ws = (char*)d_ws;
  Params* P = (Params*)(ws + 0);
  double2* part = (double2*)(ws + 4096);   // NPART*16 = 8 KB
  int* cnt = (int*)(ws + 16384);           // nblk*8*4 = 128 KB -> ends 147456
  long nblk = N / K1_THREADS;              // 4096
  int* boff = (int*)(ws + 147456);         // 128 KB -> ends 278528
  int* segsum = (int*)(ws + 278528);       // 4 KB
  int* segbase = (int*)(ws + 282624);      // 4 KB
  int nout = (int)(N / OUTBLK);            // 2048
  int* cuts = (int*)(ws + 294912);         // (nout+1)*8*4 = 65.6 KB, ends < 524288
  // out8 first so k5's tail prefetch over-read (<=128B) lands inside pay2 (safe)
  float2* out8 = (float2*)(ws + 524288);
  unsigned* pay2 = (unsigned*)(ws + 524288 + (size_t)N * 8);
  float* bt = (float*)(ws + 524288 + (size_t)N * 12);
  // total ws need: 524288 + N*8 + N*4 + N*4 (~67.6 MB for N=4.19M)

  k1_hist<<<(int)nblk, K1_THREADS, 0, stream>>>(band, cnt);
  k2a_segsum<<<(NSEG * NBAND + 255) / 256, 256, 0, stream>>>(cnt, segsum);
  k2b_scan<<<1, NSEG * NBAND, 0, stream>>>(segsum, segbase, P, lad, lag, lkp);
  k2c_boff<<<(NSEG * NBAND + 255) / 256, 256, 0, stream>>>(cnt, segbase, boff);
  k3_scatter<<<(int)nblk, K1_THREADS, 0, stream>>>(t, band, y, dg, boff, P, pay2, bt);
  int ncut = ((nout + 1) * NBAND + 63) / 64;
  k4a_cuts<<<ncut, 64, 0, stream>>>(bt, P, cuts, nout);
  k4_merge<<<nout, 256, 0, stream>>>(bt, pay2, P, cuts, out8);
  long T = N / CHUNK;  // 32768 scan threads
  k5_scan<<<(int)(T / 64), 64, 0, stream>>>(out8, P, part);
  k6_final<<<1, 64, 0, stream>>>(part, P, lad, out, N);
}